// Round 17
// baseline (1637.076 us; speedup 1.0000x reference)
//
#include <hip/hip_runtime.h>
#include <math.h>

typedef __attribute__((ext_vector_type(8))) short bf16x8;
typedef __attribute__((ext_vector_type(4))) float f32x4;
typedef __attribute__((ext_vector_type(8))) _Float16 f16x8;
typedef unsigned short ushort_t;

#define T_STEPS 64
#define BATCH   64
#define VOCAB   32000
#define EMB     512
#define HID     1024
#define G4      4096

__device__ __forceinline__ unsigned short f2bf(float x) {
    unsigned u = __builtin_bit_cast(unsigned, x);
    u += 0x7FFFu + ((u >> 16) & 1u);
    return (unsigned short)(u >> 16);
}
__device__ __forceinline__ float bf2f(unsigned short h) {
    unsigned u = ((unsigned)h) << 16;
    return __builtin_bit_cast(float, u);
}
__device__ __forceinline__ unsigned pack2(unsigned short a, unsigned short b) {
    return (unsigned)a | ((unsigned)b << 16);
}
__device__ __forceinline__ unsigned short f2h(float x) {
    return __builtin_bit_cast(unsigned short, (_Float16)x);
}
__device__ __forceinline__ float h2f(unsigned short h) {
    return (float)__builtin_bit_cast(_Float16, h);
}
__device__ __forceinline__ f32x4 ntload4(const float* p) {
    return __builtin_nontemporal_load((const f32x4*)p);
}

// packed A-fragment offset for 16x16x32 MFMA (M16 = row-groups of 16):
__device__ __forceinline__ size_t packA_off(int row, int k, int M16) {
    return ((size_t)((k >> 5) * M16 + (row >> 4))) * 512 +
           ((k & 31) >> 3) * 128 + (row & 15) * 8 + (k & 7);
}

// ---------------------------------------------------------------------------
// emb GEMM, depth-2 pipelined (round-14 win, kept).
// ---------------------------------------------------------------------------
__launch_bounds__(512, 2)
__global__ void gemm_emb(const float* __restrict__ A, const ushort_t* __restrict__ Bp,
                         float* __restrict__ C) {
    __shared__ _Float16 AhS[2][128][40];
    const int tid = threadIdx.x;
    const int row0 = blockIdx.x * 128;
    const int z = blockIdx.y;
    const int kBeg = z * 4000;
    const int kb8  = z * 500;
    C += (size_t)z * 4096 * EMB;

    const int l = tid & 63, w = tid >> 6;
    const int wm = w >> 2, wn = w & 3;
    const int lr = l & 15, lk = l >> 4;

    const int ar = tid >> 2, ak8 = (tid & 3) << 3;
    const float* Abase = A + (size_t)(row0 + ar) * VOCAB + kBeg + ak8;

    f32x4 acc[4][8];
#pragma unroll
    for (int m = 0; m < 4; ++m)
#pragma unroll
        for (int n = 0; n < 8; ++n)
#pragma unroll
            for (int r = 0; r < 4; ++r) acc[m][n][r] = 0.f;

    auto loadB = [&](int k, f16x8* dst) {
#pragma unroll
        for (int n = 0; n < 8; ++n) {
            int g = wn * 8 + n;
            dst[n] = *(const f16x8*)(Bp + ((size_t)g * 4000 + kb8 + k * 4 + lk) * 128 + lr * 8);
        }
    };
    auto loadA = [&](int k, f32x4& v0, f32x4& v1) {
        const float* ap = Abase + k * 32;
        v0 = ntload4(ap); v1 = ntload4(ap + 4);
    };
    auto storeA = [&](int buf, f32x4 v0, f32x4 v1) {
        f16x8 hv;
        hv[0] = (_Float16)v0[0]; hv[1] = (_Float16)v0[1];
        hv[2] = (_Float16)v0[2]; hv[3] = (_Float16)v0[3];
        hv[4] = (_Float16)v1[0]; hv[5] = (_Float16)v1[1];
        hv[6] = (_Float16)v1[2]; hv[7] = (_Float16)v1[3];
        *(f16x8*)&AhS[buf][ar][ak8] = hv;
    };
    auto mfmaStep = [&](int buf, f16x8* bset) {
        f16x8 a[4];
#pragma unroll
        for (int m = 0; m < 4; ++m)
            a[m] = *(const f16x8*)&AhS[buf][wm * 64 + m * 16 + lr][lk * 8];
#pragma unroll
        for (int m = 0; m < 4; ++m)
#pragma unroll
            for (int n = 0; n < 8; ++n)
                acc[m][n] = __builtin_amdgcn_mfma_f32_16x16x32_f16(a[m], bset[n], acc[m][n], 0, 0, 0);
    };

    f16x8 bA[8], bB[8];
    f32x4 a0A, a1A, a0B, a1B;
    {
        f32x4 t0, t1;
        loadA(0, t0, t1); storeA(0, t0, t1);
        loadA(1, a0A, a1A);
        loadB(0, bA); loadB(1, bB);
        __syncthreads();
    }
    for (int k = 0; k < 124; k += 2) {
        if (k + 2 < 125) loadA(k + 2, a0B, a1B);
        mfmaStep(0, bA);
        if (k + 2 < 125) loadB(k + 2, bA);
        storeA(1, a0A, a1A);
        __syncthreads();
        if (k + 3 < 125) loadA(k + 3, a0A, a1A);
        mfmaStep(1, bB);
        if (k + 3 < 125) loadB(k + 3, bB);
        if (k + 2 < 125) storeA(0, a0B, a1B);
        __syncthreads();
    }
    mfmaStep(0, bA);

    constexpr float invScale = 1.f / 256.f;
#pragma unroll
    for (int n = 0; n < 8; ++n) {
        int col = (wn * 8 + n) * 16 + lr;
#pragma unroll
        for (int m = 0; m < 4; ++m) {
            int rbase = row0 + wm * 64 + m * 16 + lk * 4;
#pragma unroll
            for (int r = 0; r < 4; ++r)
                C[(size_t)(rbase + r) * EMB + col] = acc[m][n][r] * invScale;
        }
    }
}

// ---------------------------------------------------------------------------
// fp16 GEMM (A fp32 -> LDS, B packed direct). Kept for z0x (small).
// ---------------------------------------------------------------------------
template<int BM, int BN, int NW_M, int NW_N, bool NTA, bool NTC>
__launch_bounds__(NW_M * NW_N * 64)
__global__ void gemm_a32b16(const float* __restrict__ A, const ushort_t* __restrict__ Bp,
                            float* __restrict__ C, int lda, int ldc, int K8,
                            int KCHUNK, size_t chunkStride, float invScale) {
    constexpr int THREADS = NW_M * NW_N * 64;
    constexpr int MF = BM / NW_M / 16;
    constexpr int NF = BN / NW_N / 16;
    __shared__ _Float16 AhS[BM][40];

    const int tid  = threadIdx.x;
    const int row0 = blockIdx.y * BM;
    const int gBase = blockIdx.x * (BN / 16);
    const int kBeg = blockIdx.z * KCHUNK;
    C += (size_t)blockIdx.z * chunkStride;

    const int l = tid & 63, w = tid >> 6;
    const int wm = w / NW_N, wn = w % NW_N;
    const int lr = l & 15, lk = l >> 4;

    f32x4 acc[MF][NF];
#pragma unroll
    for (int m = 0; m < MF; ++m)
#pragma unroll
        for (int n = 0; n < NF; ++n)
#pragma unroll
            for (int r = 0; r < 4; ++r) acc[m][n][r] = 0.f;

    constexpr int AI = BM * 4 / THREADS;

    for (int k0 = 0; k0 < KCHUNK; k0 += 32) {
#pragma unroll
        for (int i = 0; i < AI; ++i) {
            int f = tid + i * THREADS;
            int r = f >> 2, k8 = (f & 3) << 3;
            const float* ap = A + (size_t)(row0 + r) * lda + kBeg + k0 + k8;
            f32x4 v0, v1;
            if (NTA) { v0 = ntload4(ap); v1 = ntload4(ap + 4); }
            else     { v0 = *(const f32x4*)ap; v1 = *(const f32x4*)(ap + 4); }
            f16x8 hv;
            hv[0] = (_Float16)v0[0]; hv[1] = (_Float16)v0[1];
            hv[2] = (_Float16)v0[2]; hv[3] = (_Float16)v0[3];
            hv[4] = (_Float16)v1[0]; hv[5] = (_Float16)v1[1];
            hv[6] = (_Float16)v1[2]; hv[7] = (_Float16)v1[3];
            *(f16x8*)&AhS[r][k8] = hv;
        }
        __syncthreads();
        const size_t kRow = (size_t)((kBeg + k0) >> 3) + lk;
        f16x8 a[MF], b[NF];
#pragma unroll
        for (int n = 0; n < NF; ++n) {
            int g = gBase + wn * NF + n;
            b[n] = *(const f16x8*)(Bp + ((size_t)g * K8 + kRow) * 128 + lr * 8);
        }
#pragma unroll
        for (int m = 0; m < MF; ++m)
            a[m] = *(const f16x8*)&AhS[wm * MF * 16 + m * 16 + lr][lk * 8];
#pragma unroll
        for (int m = 0; m < MF; ++m)
#pragma unroll
            for (int n = 0; n < NF; ++n)
                acc[m][n] = __builtin_amdgcn_mfma_f32_16x16x32_f16(a[m], b[n], acc[m][n], 0, 0, 0);
        __syncthreads();
    }

#pragma unroll
    for (int n = 0; n < NF; ++n) {
        int col = (gBase + wn * NF + n) * 16 + lr;
#pragma unroll
        for (int m = 0; m < MF; ++m) {
            int rbase = row0 + wm * MF * 16 + m * 16 + lk * 4;
#pragma unroll
            for (int r = 0; r < 4; ++r) {
                float v = acc[m][n][r] * invScale;
                float* cp = &C[(size_t)(rbase + r) * ldc + col];
                if (NTC) __builtin_nontemporal_store(v, cp);
                else *cp = v;
            }
        }
    }
}

// sum 8 split-K partials
__global__ void reduce8(const float* __restrict__ zp, float* __restrict__ out, size_t cs) {
    size_t i = ((size_t)blockIdx.x * 256 + threadIdx.x) * 4;
    f32x4 a = *(const f32x4*)(zp + i);
#pragma unroll
    for (int c = 1; c < 8; ++c) {
        f32x4 b = *(const f32x4*)(zp + c * cs + i);
        a += b;
    }
    *(f32x4*)(out + i) = a;
}

// ---------------------------------------------------------------------------
// fp32 -> packed fp16 single plane (scaled x256). PERM = gate-interleave.
// ---------------------------------------------------------------------------
template<bool PERM>
__launch_bounds__(256)
__global__ void wcv16(const float* __restrict__ W, ushort_t* __restrict__ Wp,
                      int Krows, int ldW, float scale) {
    __shared__ float tile[32][33];
    const int k0 = blockIdx.x * 32;
    const int n0 = blockIdx.y * 32;
    const int tid = threadIdx.x;
#pragma unroll
    for (int i = 0; i < 4; ++i) {
        int idx = tid + i * 256;
        int r = idx >> 5, c = idx & 31;
        tile[r][c] = W[(size_t)(k0 + r) * ldW + n0 + c];
    }
    __syncthreads();
    const int rn = tid >> 3;
    const int cq = (tid & 7) * 4;
    unsigned short h[4];
#pragma unroll
    for (int j = 0; j < 4; ++j) h[j] = f2h(tile[cq + j][rn] * scale);
    const int n = n0 + rn;
    const int p = PERM ? (((n & 1023) >> 2) * 16 + (n >> 10) * 4 + (n & 3)) : n;
    const int k = k0 + cq;
    size_t off = ((size_t)(p >> 4) * (Krows >> 3) + (k >> 3)) * 128 + (p & 15) * 8 + (k & 7);
    uint2 hp; hp.x = pack2(h[0], h[1]); hp.y = pack2(h[2], h[3]);
    *(uint2*)(Wp + off) = hp;
}

// ---------------------------------------------------------------------------
// LSTM layer-step body vN: block handles NG col-groups (NG*16 cols); A-frags
// loaded once per k-slice and reused across all NG W-streams.
// red stride = NG*16 + 4.
// ---------------------------------------------------------------------------
template<int K, int NG>
__device__ __forceinline__ void lstm_bodyN(
        float* red, int cg0,
        const ushort_t* Ah, const ushort_t* Al,
        const ushort_t* Wp,
        const float* xpart, const float* bias,
        float* c_state, float* histF,
        ushort_t* d1h, ushort_t* d1l,
        ushort_t* d2h, ushort_t* d2l) {
    const int tid = threadIdx.x;
    const int l = tid & 63, w = tid >> 6;
    const int lr = l & 15, lk = l >> 4;
    constexpr int spw = K >> 8;
    constexpr int RS = NG * 16 + 4;
    const size_t lane_off = (size_t)lk * 128 + lr * 8;

    const ushort_t* wptr[NG];
#pragma unroll
    for (int g = 0; g < NG; ++g)
        wptr[g] = Wp + (size_t)(cg0 + g) * (K >> 3) * 128 + lane_off + (size_t)(w * spw) * 512;

    f32x4 acc[NG][4];
#pragma unroll
    for (int g = 0; g < NG; ++g)
#pragma unroll
        for (int m = 0; m < 4; ++m)
#pragma unroll
            for (int r = 0; r < 4; ++r) acc[g][m][r] = 0.f;

    const int s0 = w * spw;
    const ushort_t* aptr = Ah + (size_t)s0 * 4 * 512 + l * 8;
    const ushort_t* lptr = Al + (size_t)s0 * 4 * 512 + l * 8;
#pragma unroll
    for (int s = 0; s < spw; ++s) {
        f16x8 bw[NG];
#pragma unroll
        for (int g = 0; g < NG; ++g)
            bw[g] = *(const f16x8*)(wptr[g] + (size_t)s * 512);
#pragma unroll
        for (int m = 0; m < 4; ++m) {
            f16x8 ah = *(const f16x8*)(aptr + (size_t)(s * 4 + m) * 512);
            f16x8 al = *(const f16x8*)(lptr + (size_t)(s * 4 + m) * 512);
#pragma unroll
            for (int g = 0; g < NG; ++g) {
                acc[g][m] = __builtin_amdgcn_mfma_f32_16x16x32_f16(ah, bw[g], acc[g][m], 0, 0, 0);
                acc[g][m] = __builtin_amdgcn_mfma_f32_16x16x32_f16(al, bw[g], acc[g][m], 0, 0, 0);
            }
        }
    }
#pragma unroll
    for (int g = 0; g < NG; ++g)
#pragma unroll
        for (int m = 0; m < 4; ++m)
            *(f32x4*)&red[(w * 64 + l) * RS + g * 16 + m * 4] = acc[g][m];
    __syncthreads();

#pragma unroll
    for (int e = 0; e < NG / 2; ++e) {
        const int uu = tid + e * 512;
        const int gl = uu >> 8;
        const int tt = uu & 255;
        const int r = tt >> 2, v = tt & 3;
        const int m = r >> 4, lkq = (r >> 2) & 3, reg = r & 3;
        const int u = (cg0 + gl) * 4 + v;
        constexpr float invS = 1.f / 65536.f;
        float z[4];
#pragma unroll
        for (int j = 0; j < 4; ++j) {
            const int c = j * 4 + v;
            float s = 0.f;
#pragma unroll
            for (int ww = 0; ww < 8; ++ww)
                s += red[(ww * 64 + lkq * 16 + c) * RS + gl * 16 + m * 4 + reg];
            s = s * invS + bias[j * 1024 + u];
            if (xpart)
                s += __builtin_nontemporal_load(&xpart[(size_t)r * 4096 + j * 1024 + u]);
            z[j] = s;
        }
        float f = 1.f / (1.f + expf(-z[0]));
        float i = 1.f / (1.f + expf(-z[1]));
        float o = 1.f / (1.f + expf(-z[2]));
        float g = tanhf(z[3]);
        const int cidx = r * 1024 + u;
        float cn = f * c_state[cidx] + i * g;
        c_state[cidx] = cn;
        float hn = o * tanhf(cn);
        __builtin_nontemporal_store(hn, &histF[cidx]);
        float hs = hn * 256.f;
        unsigned short hh = f2h(hs);
        unsigned short hl = f2h(hs - h2f(hh));
        size_t o1 = packA_off(r, u, 4);
        d1h[o1] = hh; d1l[o1] = hl;
        if (d2h) {
            size_t o2 = packA_off(r, u, 4);
            d2h[o2] = hh; d2l[o2] = hl;
        }
    }
    __syncthreads();
}

// ---------------------------------------------------------------------------
// Pipelined pair dispatch v3: 192 blocks. 0..63 -> layer0(t), NG=4 (64 cols);
// 64..191 -> layer1(t-1), NG=2 (32 cols). Balanced per-block work.
// ---------------------------------------------------------------------------
__launch_bounds__(512)
__global__ void lstm_pair(int active0, int active1,
        const ushort_t* Ah0, const ushort_t* Al0, const ushort_t* Wp0,
        const float* xpart0, const float* bias0,
        float* c0, float* hist0,
        ushort_t* d1h0, ushort_t* d1l0, ushort_t* d2h0, ushort_t* d2l0,
        const ushort_t* Ah1, const ushort_t* Al1, const ushort_t* Wp1,
        const float* bias1, float* c1, float* hist1,
        ushort_t* d1h1, ushort_t* d1l1) {
    __shared__ float red[512 * 68];
    const int b = blockIdx.x;
    if (b < 64) {
        if (!active0) return;
        lstm_bodyN<1024, 4>(red, b * 4, Ah0, Al0, Wp0, xpart0, bias0,
                            c0, hist0, d1h0, d1l0, d2h0, d2l0);
    } else {
        if (!active1) return;
        lstm_bodyN<2048, 2>(red, (b - 64) * 2, Ah1, Al1, Wp1, nullptr, bias1,
                            c1, hist1, d1h1, d1l1, nullptr, nullptr);
    }
}

// ---------------------------------------------------------------------------
// gates + gating; emits gated as packed fp16 SINGLE A-fragment plane (x256).
// ---------------------------------------------------------------------------
__launch_bounds__(256)
__global__ void gates_gated(const float* __restrict__ h0s, const float* __restrict__ h1s,
                            const float* __restrict__ gw,
                            ushort_t* __restrict__ gA16) {
    const int r = blockIdx.x;
    const int tid = threadIdx.x;
    const float* h0r = h0s + (size_t)r * HID;
    const float* h1r = h1s + (size_t)r * HID;
    float p0 = 0.f, p1 = 0.f;
    for (int k = tid; k < HID; k += 256) {
        float v0 = h0r[k], v1 = h1r[k];
        p0 += v0 * gw[2 * k]     + v1 * gw[2 * (HID + k)];
        p1 += v0 * gw[2 * k + 1] + v1 * gw[2 * (HID + k) + 1];
    }
#pragma unroll
    for (int off = 32; off; off >>= 1) {
        p0 += __shfl_down(p0, off);
        p1 += __shfl_down(p1, off);
    }
    __shared__ float s0[4], s1[4];
    __shared__ float gg[2];
    if ((tid & 63) == 0) { s0[tid >> 6] = p0; s1[tid >> 6] = p1; }
    __syncthreads();
    if (tid == 0) {
        float a = s0[0] + s0[1] + s0[2] + s0[3];
        float b = s1[0] + s1[1] + s1[2] + s1[3];
        gg[0] = 1.f / (1.f + expf(-a));
        gg[1] = 1.f / (1.f + expf(-b));
    }
    __syncthreads();
    float g0 = gg[0], g1 = gg[1];
    const int n0 = tid * 4;
    unsigned short h[4];
#pragma unroll
    for (int j = 0; j < 4; ++j) {
        int n = n0 + j;
        h[j] = f2h((g0 * h0r[n] + g1 * h1r[n]) * 256.f);
    }
    uint2 hp; hp.x = pack2(h[0], h[1]); hp.y = pack2(h[2], h[3]);
    *(uint2*)(gA16 + packA_off(r, n0, 256)) = hp;
}

// ---------------------------------------------------------------------------
// logits GEMM v4 (round-13 best): fp16 single planes both sides, dbuf LDS
// with depth-1 register prefetch, row-major XCD swizzle, NT C stores.
// ---------------------------------------------------------------------------
__launch_bounds__(512)
__global__ void gemm_out_v4(const ushort_t* __restrict__ gA16, const ushort_t* __restrict__ Bp,
                            const float* __restrict__ bias, float* __restrict__ C) {
    __shared__ ushort_t AL[2][8192];
    __shared__ ushort_t BL[2][4096];

    const int tid = threadIdx.x;
    const int lin = (blockIdx.x & 7) * 500 + (blockIdx.x >> 3);   // 4000 % 8 == 0
    const int bi = lin / 250, bj = lin % 250;
    const int row0 = bi * 256, col0 = bj * 128;

    const int l = tid & 63, w = tid >> 6;
    const int wm = w >> 1, wn = w & 1;
    const int lr = l & 15, lk = l >> 4;

    const int aOff = tid * 8;                                 // shorts
    const size_t bBase = (size_t)(bj * 8 + (tid >> 6)) * 16384 + (tid & 63) * 8;

    f32x4 acc[4][4];
#pragma unroll
    for (int m = 0; m < 4; ++m)
#pragma unroll
        for (int n = 0; n < 4; ++n)
#pragma unroll
            for (int r = 0; r < 4; ++r) acc[m][n][r] = 0.f;

    // prologue: stage tile 0
    {
        const size_t cA = ((size_t)(bi * 16)) * 512;
        uint4 a0 = *(const uint4*)(gA16 + cA + aOff);
        uint4 a1 = *(const uint4*)(gA16 + cA + 4096 + aOff);
        uint4 b0 = *(const uint4*)(Bp + bBase);
        *(uint4*)&AL[0][aOff] = a0;
        *(uint4*)&AL[0][4096 + aOff] = a1;
        *(uint4*)&BL[0][aOff & 4095] = b0;
    }
    __syncthreads();

    uint4 rA0, rA1, rB;
    for (int k32 = 0; k32 < 32; ++k32) {
        const int cur = k32 & 1, nxt = cur ^ 1;
        const bool hasNext = (k32 < 31);
        if (hasNext) {
            const size_t cA = ((size_t)((k32 + 1) * 256 + bi * 16)) * 512;
            rA0 = *(const uint4*)(gA16 + cA + aOff);
            rA1 = *(const uint4*)(gA16 + cA + 4096 + aOff);
            rB  = *(const uint4*)(Bp + bBase + (size_t)(k32 + 1) * 512);
        }
        f16x8 a[4], b[4];
#pragma unroll
        for (int m = 0; m < 4; ++m)
            a[m] = *(const f16x8*)&AL[cur][(wm * 4 + m) * 512 + l * 8];
#pragma unroll
        for (int n = 0; n < 4; ++n)
            b[n] = *(const f16x8*)&BL[cur][(wn * 4 + n) * 512 + l * 8];
#pragma unroll
        for (int m = 0; m < 4; ++m)
#pragma unroll
            for (int n = 0; n < 4; ++n)
                acc[m][n] = __builtin_amdgcn_mfma_f32_16x16x32_f16(a[m], b[n], acc[m][n], 0, 0, 0);
        if (hasNext) {
            *(uint4*)&AL[nxt][aOff] = rA0;
            *(uint4*)&AL[nxt][4096 + aOff] = rA1;
            *(uint4*)&BL[nxt][aOff & 4095] = rB;
        }
        __syncthreads();
    }

    constexpr float invScale = 1.f / 65536.f;
#pragma unroll
    for (int n = 0; n < 4; ++n) {
        int col = col0 + wn * 64 + n * 16 + lr;
        float bv = bias[col];
#pragma unroll
        for (int m = 0; m < 4; ++m) {
            int rbase = row0 + wm * 64 + m * 16 + lk * 4;
#pragma unroll
            for (int r = 0; r < 4; ++r)
                __builtin_nontemporal_store(acc[m][n][r] * invScale + bv,
                                            &C[(size_t)(rbase + r) * VOCAB + col]);
        }
    }
}

// ---------------------------------------------------------------------------
extern "C" void kernel_launch(void* const* d_in, const int* in_sizes, int n_in,
                              void* d_out, int out_size, void* d_ws, size_t ws_size,
                              hipStream_t stream) {
    const float* inputs = (const float*)d_in[0];
    const float* embm   = (const float*)d_in[1];
    const float* w0     = (const float*)d_in[2];
    const float* b0     = (const float*)d_in[3];
    const float* w1     = (const float*)d_in[4];
    const float* b1     = (const float*)d_in[5];
    const float* gw     = (const float*)d_in[6];
    const float* outw   = (const float*)d_in[7];
    const float* outb   = (const float*)d_in[8];
    float* logits = (float*)d_out;

    // ---- workspace layout (floats) ----
    float* ws    = (float*)d_ws;
    float* emb   = ws;                          // 2,097,152
    float* h0s   = ws + 2097152;                // 4,194,304
    float* h1s   = ws + 6291456;                // 4,194,304
    ushort_t* gA16 = (ushort_t*)(ws + 10485760); // 4,194,304 shorts
    float* c0    = ws + 14942208;               // 65,536
    float* c1    = ws + 15007744;               // 65,536
    ushort_t* hpB = (ushort_t*)(ws + 15073280); // 786,432 shorts
    ushort_t* outw16 = (ushort_t*)(ws + 15466496); // 32,768,000 shorts

    ushort_t* hp0h[2] = { hpB,            hpB + 65536 };
    ushort_t* hp0l[2] = { hpB + 131072,   hpB + 196608 };
    ushort_t* hp1h[2] = { hpB + 262144,   hpB + 393216 };
    ushort_t* hp1l[2] = { hpB + 524288,   hpB + 655360 };

    // ---- d_out doubles as scratch before logits ----
    float* zpEmb = (float*)d_out;                            // 16,777,216 f
    float* z0x   = (float*)d_out + 16777216;                 // 16,777,216 f
    ushort_t* wt0 = (ushort_t*)((float*)d_out + 33554432);   // 4,194,304 shorts
    ushort_t* wt1 = wt0 + 4194304;                           // 8,388,608 shorts
    ushort_t* embm16 = wt1 + 8388608;                        // 16,384,000 shorts
    ushort_t* w0x16  = embm16 + 16384000;                    // 2,097,152 shorts

    // zero c0, c1, h packed planes (contiguous region)
    (void)hipMemsetAsync(c0, 0, (size_t)524288 * sizeof(float), stream);

    // pre-convert operands to packed fp16 planes (scaled x256)
    wcv16<false><<<dim3(1000, 16), 256, 0, stream>>>(embm, embm16, VOCAB, EMB, 256.f);
    wcv16<false><<<dim3(16, 128), 256, 0, stream>>>(w0, w0x16, EMB, G4, 256.f);
    wcv16<false><<<dim3(32, 1000), 256, 0, stream>>>(outw, outw16, HID, VOCAB, 256.f);
    // LSTM weights -> fp16 single, gate-interleaved packed planes
    wcv16<true><<<dim3(32, 128), 256, 0, stream>>>(w0 + (size_t)512 * G4, wt0, 1024, G4, 256.f);
    wcv16<true><<<dim3(64, 128), 256, 0, stream>>>(w1, wt1, 2048, G4, 256.f);

    // emb = inputs @ embm : split-K x8, depth-2 pipelined
    gemm_emb<<<dim3(32, 8), 512, 0, stream>>>(inputs, embm16, zpEmb);
    reduce8<<<2048, 256, 0, stream>>>(zpEmb, emb, (size_t)4096 * EMB);

    // z0x = emb @ w0[:512,:]  (original column order; NT C stores)
    gemm_a32b16<128, 128, 2, 2, false, true><<<dim3(32, 32, 1), 256, 0, stream>>>(
        emb, w0x16, z0x, EMB, G4, EMB / 8, EMB, 0, 1.f / 256.f);

    // pipelined LSTM: dispatch t runs layer0(t) || layer1(t-1); 65 dispatches
    for (int t = 0; t <= T_STEPS; ++t) {
        const int p0 = t & 1, q0 = (t + 1) & 1;
        const int s  = t - 1, ss = s < 0 ? 0 : s;
        const int p1 = ss & 1, q1 = (ss + 1) & 1;
        lstm_pair<<<192, 512, 0, stream>>>(
            (t < T_STEPS) ? 1 : 0, (t >= 1) ? 1 : 0,
            hp0h[p0], hp0l[p0], wt0,
            z0x + (size_t)(t < T_STEPS ? t : 0) * 262144, b0,
            c0, h0s + (size_t)(t < T_STEPS ? t : 0) * 65536,
            hp0h[q0], hp0l[q0], hp1h[p0], hp1l[p0],
            hp1h[p1], hp1l[p1], wt1,
            b1, c1, h1s + (size_t)ss * 65536,
            hp1h[q1] + 65536, hp1l[q1] + 65536);
    }

    // gating -> packed fp16 single A plane (x256)
    gates_gated<<<4096, 256, 0, stream>>>(h0s, h1s, gw, gA16);

    // logits = gated @ outw + outb  (fp16 single both sides, NT C stores)
    gemm_out_v4<<<4000, 512, 0, stream>>>(gA16, outw16, outb, logits);
}

// Round 18
// 1488.037 us; speedup vs baseline: 1.1002x; 1.1002x over previous
//
#include <hip/hip_runtime.h>
#include <math.h>

typedef __attribute__((ext_vector_type(8))) short bf16x8;
typedef __attribute__((ext_vector_type(4))) float f32x4;
typedef __attribute__((ext_vector_type(8))) _Float16 f16x8;
typedef unsigned short ushort_t;

#define T_STEPS 64
#define BATCH   64
#define VOCAB   32000
#define EMB     512
#define HID     1024
#define G4      4096

__device__ __forceinline__ unsigned short f2bf(float x) {
    unsigned u = __builtin_bit_cast(unsigned, x);
    u += 0x7FFFu + ((u >> 16) & 1u);
    return (unsigned short)(u >> 16);
}
__device__ __forceinline__ float bf2f(unsigned short h) {
    unsigned u = ((unsigned)h) << 16;
    return __builtin_bit_cast(float, u);
}
__device__ __forceinline__ unsigned pack2(unsigned short a, unsigned short b) {
    return (unsigned)a | ((unsigned)b << 16);
}
__device__ __forceinline__ unsigned short f2h(float x) {
    return __builtin_bit_cast(unsigned short, (_Float16)x);
}
__device__ __forceinline__ float h2f(unsigned short h) {
    return (float)__builtin_bit_cast(_Float16, h);
}
__device__ __forceinline__ f32x4 ntload4(const float* p) {
    return __builtin_nontemporal_load((const f32x4*)p);
}

// packed A-fragment offset for 16x16x32 MFMA (M16 = row-groups of 16):
__device__ __forceinline__ size_t packA_off(int row, int k, int M16) {
    return ((size_t)((k >> 5) * M16 + (row >> 4))) * 512 +
           ((k & 31) >> 3) * 128 + (row & 15) * 8 + (k & 7);
}

// ---------------------------------------------------------------------------
// emb GEMM, depth-2 pipelined (round-14 win, kept).
// ---------------------------------------------------------------------------
__launch_bounds__(512, 2)
__global__ void gemm_emb(const float* __restrict__ A, const ushort_t* __restrict__ Bp,
                         float* __restrict__ C) {
    __shared__ _Float16 AhS[2][128][40];
    const int tid = threadIdx.x;
    const int row0 = blockIdx.x * 128;
    const int z = blockIdx.y;
    const int kBeg = z * 4000;
    const int kb8  = z * 500;
    C += (size_t)z * 4096 * EMB;

    const int l = tid & 63, w = tid >> 6;
    const int wm = w >> 2, wn = w & 3;
    const int lr = l & 15, lk = l >> 4;

    const int ar = tid >> 2, ak8 = (tid & 3) << 3;
    const float* Abase = A + (size_t)(row0 + ar) * VOCAB + kBeg + ak8;

    f32x4 acc[4][8];
#pragma unroll
    for (int m = 0; m < 4; ++m)
#pragma unroll
        for (int n = 0; n < 8; ++n)
#pragma unroll
            for (int r = 0; r < 4; ++r) acc[m][n][r] = 0.f;

    auto loadB = [&](int k, f16x8* dst) {
#pragma unroll
        for (int n = 0; n < 8; ++n) {
            int g = wn * 8 + n;
            dst[n] = *(const f16x8*)(Bp + ((size_t)g * 4000 + kb8 + k * 4 + lk) * 128 + lr * 8);
        }
    };
    auto loadA = [&](int k, f32x4& v0, f32x4& v1) {
        const float* ap = Abase + k * 32;
        v0 = ntload4(ap); v1 = ntload4(ap + 4);
    };
    auto storeA = [&](int buf, f32x4 v0, f32x4 v1) {
        f16x8 hv;
        hv[0] = (_Float16)v0[0]; hv[1] = (_Float16)v0[1];
        hv[2] = (_Float16)v0[2]; hv[3] = (_Float16)v0[3];
        hv[4] = (_Float16)v1[0]; hv[5] = (_Float16)v1[1];
        hv[6] = (_Float16)v1[2]; hv[7] = (_Float16)v1[3];
        *(f16x8*)&AhS[buf][ar][ak8] = hv;
    };
    auto mfmaStep = [&](int buf, f16x8* bset) {
        f16x8 a[4];
#pragma unroll
        for (int m = 0; m < 4; ++m)
            a[m] = *(const f16x8*)&AhS[buf][wm * 64 + m * 16 + lr][lk * 8];
#pragma unroll
        for (int m = 0; m < 4; ++m)
#pragma unroll
            for (int n = 0; n < 8; ++n)
                acc[m][n] = __builtin_amdgcn_mfma_f32_16x16x32_f16(a[m], bset[n], acc[m][n], 0, 0, 0);
    };

    f16x8 bA[8], bB[8];
    f32x4 a0A, a1A, a0B, a1B;
    {
        f32x4 t0, t1;
        loadA(0, t0, t1); storeA(0, t0, t1);
        loadA(1, a0A, a1A);
        loadB(0, bA); loadB(1, bB);
        __syncthreads();
    }
    for (int k = 0; k < 124; k += 2) {
        if (k + 2 < 125) loadA(k + 2, a0B, a1B);
        mfmaStep(0, bA);
        if (k + 2 < 125) loadB(k + 2, bA);
        storeA(1, a0A, a1A);
        __syncthreads();
        if (k + 3 < 125) loadA(k + 3, a0A, a1A);
        mfmaStep(1, bB);
        if (k + 3 < 125) loadB(k + 3, bB);
        if (k + 2 < 125) storeA(0, a0B, a1B);
        __syncthreads();
    }
    mfmaStep(0, bA);

    constexpr float invScale = 1.f / 256.f;
#pragma unroll
    for (int n = 0; n < 8; ++n) {
        int col = (wn * 8 + n) * 16 + lr;
#pragma unroll
        for (int m = 0; m < 4; ++m) {
            int rbase = row0 + wm * 64 + m * 16 + lk * 4;
#pragma unroll
            for (int r = 0; r < 4; ++r)
                C[(size_t)(rbase + r) * EMB + col] = acc[m][n][r] * invScale;
        }
    }
}

// ---------------------------------------------------------------------------
// fp16 GEMM (A fp32 -> LDS, B packed direct). Kept for z0x (small).
// ---------------------------------------------------------------------------
template<int BM, int BN, int NW_M, int NW_N, bool NTA, bool NTC>
__launch_bounds__(NW_M * NW_N * 64)
__global__ void gemm_a32b16(const float* __restrict__ A, const ushort_t* __restrict__ Bp,
                            float* __restrict__ C, int lda, int ldc, int K8,
                            int KCHUNK, size_t chunkStride, float invScale) {
    constexpr int THREADS = NW_M * NW_N * 64;
    constexpr int MF = BM / NW_M / 16;
    constexpr int NF = BN / NW_N / 16;
    __shared__ _Float16 AhS[BM][40];

    const int tid  = threadIdx.x;
    const int row0 = blockIdx.y * BM;
    const int gBase = blockIdx.x * (BN / 16);
    const int kBeg = blockIdx.z * KCHUNK;
    C += (size_t)blockIdx.z * chunkStride;

    const int l = tid & 63, w = tid >> 6;
    const int wm = w / NW_N, wn = w % NW_N;
    const int lr = l & 15, lk = l >> 4;

    f32x4 acc[MF][NF];
#pragma unroll
    for (int m = 0; m < MF; ++m)
#pragma unroll
        for (int n = 0; n < NF; ++n)
#pragma unroll
            for (int r = 0; r < 4; ++r) acc[m][n][r] = 0.f;

    constexpr int AI = BM * 4 / THREADS;

    for (int k0 = 0; k0 < KCHUNK; k0 += 32) {
#pragma unroll
        for (int i = 0; i < AI; ++i) {
            int f = tid + i * THREADS;
            int r = f >> 2, k8 = (f & 3) << 3;
            const float* ap = A + (size_t)(row0 + r) * lda + kBeg + k0 + k8;
            f32x4 v0, v1;
            if (NTA) { v0 = ntload4(ap); v1 = ntload4(ap + 4); }
            else     { v0 = *(const f32x4*)ap; v1 = *(const f32x4*)(ap + 4); }
            f16x8 hv;
            hv[0] = (_Float16)v0[0]; hv[1] = (_Float16)v0[1];
            hv[2] = (_Float16)v0[2]; hv[3] = (_Float16)v0[3];
            hv[4] = (_Float16)v1[0]; hv[5] = (_Float16)v1[1];
            hv[6] = (_Float16)v1[2]; hv[7] = (_Float16)v1[3];
            *(f16x8*)&AhS[r][k8] = hv;
        }
        __syncthreads();
        const size_t kRow = (size_t)((kBeg + k0) >> 3) + lk;
        f16x8 a[MF], b[NF];
#pragma unroll
        for (int n = 0; n < NF; ++n) {
            int g = gBase + wn * NF + n;
            b[n] = *(const f16x8*)(Bp + ((size_t)g * K8 + kRow) * 128 + lr * 8);
        }
#pragma unroll
        for (int m = 0; m < MF; ++m)
            a[m] = *(const f16x8*)&AhS[wm * MF * 16 + m * 16 + lr][lk * 8];
#pragma unroll
        for (int m = 0; m < MF; ++m)
#pragma unroll
            for (int n = 0; n < NF; ++n)
                acc[m][n] = __builtin_amdgcn_mfma_f32_16x16x32_f16(a[m], b[n], acc[m][n], 0, 0, 0);
        __syncthreads();
    }

#pragma unroll
    for (int n = 0; n < NF; ++n) {
        int col = (gBase + wn * NF + n) * 16 + lr;
#pragma unroll
        for (int m = 0; m < MF; ++m) {
            int rbase = row0 + wm * MF * 16 + m * 16 + lk * 4;
#pragma unroll
            for (int r = 0; r < 4; ++r) {
                float v = acc[m][n][r] * invScale;
                float* cp = &C[(size_t)(rbase + r) * ldc + col];
                if (NTC) __builtin_nontemporal_store(v, cp);
                else *cp = v;
            }
        }
    }
}

// sum 8 split-K partials
__global__ void reduce8(const float* __restrict__ zp, float* __restrict__ out, size_t cs) {
    size_t i = ((size_t)blockIdx.x * 256 + threadIdx.x) * 4;
    f32x4 a = *(const f32x4*)(zp + i);
#pragma unroll
    for (int c = 1; c < 8; ++c) {
        f32x4 b = *(const f32x4*)(zp + c * cs + i);
        a += b;
    }
    *(f32x4*)(out + i) = a;
}

// ---------------------------------------------------------------------------
// fp32 -> packed fp16 single plane (scaled x256). PERM = gate-interleave.
// ---------------------------------------------------------------------------
template<bool PERM>
__launch_bounds__(256)
__global__ void wcv16(const float* __restrict__ W, ushort_t* __restrict__ Wp,
                      int Krows, int ldW, float scale) {
    __shared__ float tile[32][33];
    const int k0 = blockIdx.x * 32;
    const int n0 = blockIdx.y * 32;
    const int tid = threadIdx.x;
#pragma unroll
    for (int i = 0; i < 4; ++i) {
        int idx = tid + i * 256;
        int r = idx >> 5, c = idx & 31;
        tile[r][c] = W[(size_t)(k0 + r) * ldW + n0 + c];
    }
    __syncthreads();
    const int rn = tid >> 3;
    const int cq = (tid & 7) * 4;
    unsigned short h[4];
#pragma unroll
    for (int j = 0; j < 4; ++j) h[j] = f2h(tile[cq + j][rn] * scale);
    const int n = n0 + rn;
    const int p = PERM ? (((n & 1023) >> 2) * 16 + (n >> 10) * 4 + (n & 3)) : n;
    const int k = k0 + cq;
    size_t off = ((size_t)(p >> 4) * (Krows >> 3) + (k >> 3)) * 128 + (p & 15) * 8 + (k & 7);
    uint2 hp; hp.x = pack2(h[0], h[1]); hp.y = pack2(h[2], h[3]);
    *(uint2*)(Wp + off) = hp;
}

// ---------------------------------------------------------------------------
// LSTM layer-step body v2 (round-16 best): block handles 32 cols (2 groups),
// A-fragments loaded once, reused for both W column sets. red stride 36.
// ---------------------------------------------------------------------------
template<int K>
__device__ __forceinline__ void lstm_body2(
        float* red, int cg0,
        const ushort_t* Ah, const ushort_t* Al,
        const ushort_t* Wp,
        const float* xpart, const float* bias,
        float* c_state, float* histF,
        ushort_t* d1h, ushort_t* d1l,
        ushort_t* d2h, ushort_t* d2l) {
    const int tid = threadIdx.x;
    const int l = tid & 63, w = tid >> 6;
    const int lr = l & 15, lk = l >> 4;
    constexpr int spw = K >> 8;
    const size_t lane_off = (size_t)lk * 128 + lr * 8;
    const size_t wb0 = (size_t)cg0 * (K >> 3) * 128 + lane_off;
    const size_t wb1 = (size_t)(cg0 + 1) * (K >> 3) * 128 + lane_off;

    f32x4 acc0[4], acc1[4];
#pragma unroll
    for (int m = 0; m < 4; ++m)
#pragma unroll
        for (int r = 0; r < 4; ++r) { acc0[m][r] = 0.f; acc1[m][r] = 0.f; }

    const int s0 = w * spw;
    const ushort_t* wptr0 = Wp + wb0 + (size_t)s0 * 512;
    const ushort_t* wptr1 = Wp + wb1 + (size_t)s0 * 512;
    const ushort_t* aptr = Ah + (size_t)s0 * 4 * 512 + l * 8;
    const ushort_t* lptr = Al + (size_t)s0 * 4 * 512 + l * 8;
#pragma unroll
    for (int s = 0; s < spw; ++s) {
        f16x8 bw0 = *(const f16x8*)(wptr0 + (size_t)s * 512);
        f16x8 bw1 = *(const f16x8*)(wptr1 + (size_t)s * 512);
#pragma unroll
        for (int m = 0; m < 4; ++m) {
            f16x8 ah = *(const f16x8*)(aptr + (size_t)(s * 4 + m) * 512);
            f16x8 al = *(const f16x8*)(lptr + (size_t)(s * 4 + m) * 512);
            acc0[m] = __builtin_amdgcn_mfma_f32_16x16x32_f16(ah, bw0, acc0[m], 0, 0, 0);
            acc0[m] = __builtin_amdgcn_mfma_f32_16x16x32_f16(al, bw0, acc0[m], 0, 0, 0);
            acc1[m] = __builtin_amdgcn_mfma_f32_16x16x32_f16(ah, bw1, acc1[m], 0, 0, 0);
            acc1[m] = __builtin_amdgcn_mfma_f32_16x16x32_f16(al, bw1, acc1[m], 0, 0, 0);
        }
    }
#pragma unroll
    for (int m = 0; m < 4; ++m) {
        *(f32x4*)&red[(w * 64 + l) * 36 + m * 4]      = acc0[m];
        *(f32x4*)&red[(w * 64 + l) * 36 + 16 + m * 4] = acc1[m];
    }
    __syncthreads();

    {
        const int gl = tid >> 8;
        const int tt = tid & 255;
        const int r = tt >> 2, v = tt & 3;
        const int m = r >> 4, lkq = (r >> 2) & 3, reg = r & 3;
        const int u = (cg0 + gl) * 4 + v;
        constexpr float invS = 1.f / 65536.f;
        float z[4];
#pragma unroll
        for (int j = 0; j < 4; ++j) {
            const int c = j * 4 + v;
            float s = 0.f;
#pragma unroll
            for (int ww = 0; ww < 8; ++ww)
                s += red[(ww * 64 + lkq * 16 + c) * 36 + gl * 16 + m * 4 + reg];
            s = s * invS + bias[j * 1024 + u];
            if (xpart)
                s += __builtin_nontemporal_load(&xpart[(size_t)r * 4096 + j * 1024 + u]);
            z[j] = s;
        }
        float f = 1.f / (1.f + expf(-z[0]));
        float i = 1.f / (1.f + expf(-z[1]));
        float o = 1.f / (1.f + expf(-z[2]));
        float g = tanhf(z[3]);
        const int cidx = r * 1024 + u;
        float cn = f * c_state[cidx] + i * g;
        c_state[cidx] = cn;
        float hn = o * tanhf(cn);
        __builtin_nontemporal_store(hn, &histF[cidx]);
        float hs = hn * 256.f;
        unsigned short hh = f2h(hs);
        unsigned short hl = f2h(hs - h2f(hh));
        size_t o1 = packA_off(r, u, 4);
        d1h[o1] = hh; d1l[o1] = hl;
        if (d2h) {
            size_t o2 = packA_off(r, u, 4);
            d2h[o2] = hh; d2l[o2] = hl;
        }
    }
    __syncthreads();
}

// ---------------------------------------------------------------------------
// Pipelined pair dispatch (round-16 best): 256 blocks; 0..127 -> layer0(t),
// 128..255 -> layer1(t-1), 32 cols each.
// ---------------------------------------------------------------------------
__launch_bounds__(512)
__global__ void lstm_pair(int active0, int active1,
        const ushort_t* Ah0, const ushort_t* Al0, const ushort_t* Wp0,
        const float* xpart0, const float* bias0,
        float* c0, float* hist0,
        ushort_t* d1h0, ushort_t* d1l0, ushort_t* d2h0, ushort_t* d2l0,
        const ushort_t* Ah1, const ushort_t* Al1, const ushort_t* Wp1,
        const float* bias1, float* c1, float* hist1,
        ushort_t* d1h1, ushort_t* d1l1) {
    __shared__ float red[512 * 36];
    const int b = blockIdx.x;
    if (b < 128) {
        if (!active0) return;
        lstm_body2<1024>(red, b * 2, Ah0, Al0, Wp0, xpart0, bias0,
                         c0, hist0, d1h0, d1l0, d2h0, d2l0);
    } else {
        if (!active1) return;
        lstm_body2<2048>(red, (b - 128) * 2, Ah1, Al1, Wp1, nullptr, bias1,
                         c1, hist1, d1h1, d1l1, nullptr, nullptr);
    }
}

// ---------------------------------------------------------------------------
// gates + gating; emits gated as packed fp16 SINGLE A-fragment plane (x256).
// ---------------------------------------------------------------------------
__launch_bounds__(256)
__global__ void gates_gated(const float* __restrict__ h0s, const float* __restrict__ h1s,
                            const float* __restrict__ gw,
                            ushort_t* __restrict__ gA16) {
    const int r = blockIdx.x;
    const int tid = threadIdx.x;
    const float* h0r = h0s + (size_t)r * HID;
    const float* h1r = h1s + (size_t)r * HID;
    float p0 = 0.f, p1 = 0.f;
    for (int k = tid; k < HID; k += 256) {
        float v0 = h0r[k], v1 = h1r[k];
        p0 += v0 * gw[2 * k]     + v1 * gw[2 * (HID + k)];
        p1 += v0 * gw[2 * k + 1] + v1 * gw[2 * (HID + k) + 1];
    }
#pragma unroll
    for (int off = 32; off; off >>= 1) {
        p0 += __shfl_down(p0, off);
        p1 += __shfl_down(p1, off);
    }
    __shared__ float s0[4], s1[4];
    __shared__ float gg[2];
    if ((tid & 63) == 0) { s0[tid >> 6] = p0; s1[tid >> 6] = p1; }
    __syncthreads();
    if (tid == 0) {
        float a = s0[0] + s0[1] + s0[2] + s0[3];
        float b = s1[0] + s1[1] + s1[2] + s1[3];
        gg[0] = 1.f / (1.f + expf(-a));
        gg[1] = 1.f / (1.f + expf(-b));
    }
    __syncthreads();
    float g0 = gg[0], g1 = gg[1];
    const int n0 = tid * 4;
    unsigned short h[4];
#pragma unroll
    for (int j = 0; j < 4; ++j) {
        int n = n0 + j;
        h[j] = f2h((g0 * h0r[n] + g1 * h1r[n]) * 256.f);
    }
    uint2 hp; hp.x = pack2(h[0], h[1]); hp.y = pack2(h[2], h[3]);
    *(uint2*)(gA16 + packA_off(r, n0, 256)) = hp;
}

// ---------------------------------------------------------------------------
// logits GEMM v6: 2 row-passes per block sharing the same B column tile
// (second pass's B loads hit this XCD's L2) -> halves B re-stream.
// Grid 2000 = 8 XCD x 250 col tiles. fp16 single planes, dbuf LDS,
// depth-1 reg prefetch, NT C stores.
// ---------------------------------------------------------------------------
__launch_bounds__(512)
__global__ void gemm_out_v6(const ushort_t* __restrict__ gA16, const ushort_t* __restrict__ Bp,
                            const float* __restrict__ bias, float* __restrict__ C) {
    __shared__ ushort_t AL[2][8192];
    __shared__ ushort_t BL[2][4096];

    const int tid = threadIdx.x;
    const int lin = (blockIdx.x & 7) * 250 + (blockIdx.x >> 3);   // 2000 % 8 == 0
    const int bi0 = lin / 250, bj = lin % 250;
    const int col0 = bj * 128;

    const int l = tid & 63, w = tid >> 6;
    const int wm = w >> 1, wn = w & 1;
    const int lr = l & 15, lk = l >> 4;

    const int aOff = tid * 8;
    const size_t bBase = (size_t)(bj * 8 + (tid >> 6)) * 16384 + (tid & 63) * 8;

#pragma unroll 1
    for (int h = 0; h < 2; ++h) {
        const int bi = bi0 * 2 + h;
        const int row0 = bi * 256;

        f32x4 acc[4][4];
#pragma unroll
        for (int m = 0; m < 4; ++m)
#pragma unroll
            for (int n = 0; n < 4; ++n)
#pragma unroll
                for (int r = 0; r < 4; ++r) acc[m][n][r] = 0.f;

        // prologue: stage tile 0
        {
            const size_t cA = ((size_t)(bi * 16)) * 512;
            uint4 a0 = *(const uint4*)(gA16 + cA + aOff);
            uint4 a1 = *(const uint4*)(gA16 + cA + 4096 + aOff);
            uint4 b0 = *(const uint4*)(Bp + bBase);
            *(uint4*)&AL[0][aOff] = a0;
            *(uint4*)&AL[0][4096 + aOff] = a1;
            *(uint4*)&BL[0][aOff & 4095] = b0;
        }
        __syncthreads();

        uint4 rA0, rA1, rB;
        for (int k32 = 0; k32 < 32; ++k32) {
            const int cur = k32 & 1, nxt = cur ^ 1;
            const bool hasNext = (k32 < 31);
            if (hasNext) {
                const size_t cA = ((size_t)((k32 + 1) * 256 + bi * 16)) * 512;
                rA0 = *(const uint4*)(gA16 + cA + aOff);
                rA1 = *(const uint4*)(gA16 + cA + 4096 + aOff);
                rB  = *(const uint4*)(Bp + bBase + (size_t)(k32 + 1) * 512);
            }
            f16x8 a[4], b[4];
#pragma unroll
            for (int m = 0; m < 4; ++m)
                a[m] = *(const f16x8*)&AL[cur][(wm * 4 + m) * 512 + l * 8];
#pragma unroll
            for (int n = 0; n < 4; ++n)
                b[n] = *(const f16x8*)&BL[cur][(wn * 4 + n) * 512 + l * 8];
#pragma unroll
            for (int m = 0; m < 4; ++m)
#pragma unroll
                for (int n = 0; n < 4; ++n)
                    acc[m][n] = __builtin_amdgcn_mfma_f32_16x16x32_f16(a[m], b[n], acc[m][n], 0, 0, 0);
            if (hasNext) {
                *(uint4*)&AL[nxt][aOff] = rA0;
                *(uint4*)&AL[nxt][4096 + aOff] = rA1;
                *(uint4*)&BL[nxt][aOff & 4095] = rB;
            }
            __syncthreads();
        }

        constexpr float invScale = 1.f / 65536.f;
#pragma unroll
        for (int n = 0; n < 4; ++n) {
            int col = col0 + wn * 64 + n * 16 + lr;
            float bv = bias[col];
#pragma unroll
            for (int m = 0; m < 4; ++m) {
                int rbase = row0 + wm * 64 + m * 16 + lk * 4;
#pragma unroll
                for (int r = 0; r < 4; ++r)
                    __builtin_nontemporal_store(acc[m][n][r] * invScale + bv,
                                                &C[(size_t)(rbase + r) * VOCAB + col]);
            }
        }
        __syncthreads();
    }
}

// ---------------------------------------------------------------------------
extern "C" void kernel_launch(void* const* d_in, const int* in_sizes, int n_in,
                              void* d_out, int out_size, void* d_ws, size_t ws_size,
                              hipStream_t stream) {
    const float* inputs = (const float*)d_in[0];
    const float* embm   = (const float*)d_in[1];
    const float* w0     = (const float*)d_in[2];
    const float* b0     = (const float*)d_in[3];
    const float* w1     = (const float*)d_in[4];
    const float* b1     = (const float*)d_in[5];
    const float* gw     = (const float*)d_in[6];
    const float* outw   = (const float*)d_in[7];
    const float* outb   = (const float*)d_in[8];
    float* logits = (float*)d_out;

    // ---- workspace layout (floats) ----
    float* ws    = (float*)d_ws;
    float* emb   = ws;                          // 2,097,152
    float* h0s   = ws + 2097152;                // 4,194,304
    float* h1s   = ws + 6291456;                // 4,194,304
    ushort_t* gA16 = (ushort_t*)(ws + 10485760); // 4,194,304 shorts
    float* c0    = ws + 14942208;               // 65,536
    float* c1    = ws + 15007744;               // 65,536
    ushort_t* hpB = (ushort_t*)(ws + 15073280); // 786,432 shorts
    ushort_t* outw16 = (ushort_t*)(ws + 15466496); // 32,768,000 shorts

    ushort_t* hp0h[2] = { hpB,            hpB + 65536 };
    ushort_t* hp0l[2] = { hpB + 131072,   hpB + 196608 };
    ushort_t* hp1h[2] = { hpB + 262144,   hpB + 393216 };
    ushort_t* hp1l[2] = { hpB + 524288,   hpB + 655360 };

    // ---- d_out doubles as scratch before logits ----
    float* zpEmb = (float*)d_out;                            // 16,777,216 f
    float* z0x   = (float*)d_out + 16777216;                 // 16,777,216 f
    ushort_t* wt0 = (ushort_t*)((float*)d_out + 33554432);   // 4,194,304 shorts
    ushort_t* wt1 = wt0 + 4194304;                           // 8,388,608 shorts
    ushort_t* embm16 = wt1 + 8388608;                        // 16,384,000 shorts
    ushort_t* w0x16  = embm16 + 16384000;                    // 2,097,152 shorts

    // zero c0, c1, h packed planes (contiguous region)
    (void)hipMemsetAsync(c0, 0, (size_t)524288 * sizeof(float), stream);

    // pre-convert operands to packed fp16 planes (scaled x256)
    wcv16<false><<<dim3(1000, 16), 256, 0, stream>>>(embm, embm16, VOCAB, EMB, 256.f);
    wcv16<false><<<dim3(16, 128), 256, 0, stream>>>(w0, w0x16, EMB, G4, 256.f);
    wcv16<false><<<dim3(32, 1000), 256, 0, stream>>>(outw, outw16, HID, VOCAB, 256.f);
    // LSTM weights -> fp16 single, gate-interleaved packed planes
    wcv16<true><<<dim3(32, 128), 256, 0, stream>>>(w0 + (size_t)512 * G4, wt0, 1024, G4, 256.f);
    wcv16<true><<<dim3(64, 128), 256, 0, stream>>>(w1, wt1, 2048, G4, 256.f);

    // emb = inputs @ embm : split-K x8, depth-2 pipelined
    gemm_emb<<<dim3(32, 8), 512, 0, stream>>>(inputs, embm16, zpEmb);
    reduce8<<<2048, 256, 0, stream>>>(zpEmb, emb, (size_t)4096 * EMB);

    // z0x = emb @ w0[:512,:]  (original column order; NT C stores)
    gemm_a32b16<128, 128, 2, 2, false, true><<<dim3(32, 32, 1), 256, 0, stream>>>(
        emb, w0x16, z0x, EMB, G4, EMB / 8, EMB, 0, 1.f / 256.f);

    // pipelined LSTM: dispatch t runs layer0(t) || layer1(t-1); 65 dispatches
    for (int t = 0; t <= T_STEPS; ++t) {
        const int p0 = t & 1, q0 = (t + 1) & 1;
        const int s  = t - 1, ss = s < 0 ? 0 : s;
        const int p1 = ss & 1, q1 = (ss + 1) & 1;
        lstm_pair<<<256, 512, 0, stream>>>(
            (t < T_STEPS) ? 1 : 0, (t >= 1) ? 1 : 0,
            hp0h[p0], hp0l[p0], wt0,
            z0x + (size_t)(t < T_STEPS ? t : 0) * 262144, b0,
            c0, h0s + (size_t)(t < T_STEPS ? t : 0) * 65536,
            hp0h[q0], hp0l[q0], hp1h[p0], hp1l[p0],
            hp1h[p1], hp1l[p1], wt1,
            b1, c1, h1s + (size_t)ss * 65536,
            hp1h[q1] + 65536, hp1l[q1] + 65536);
    }

    // gating -> packed fp16 single A plane (x256)
    gates_gated<<<4096, 256, 0, stream>>>(h0s, h1s, gw, gA16);

    // logits = gated @ outw + outb  (fp16 single both sides, NT C stores)
    gemm_out_v6<<<2000, 512, 0, stream>>>(gA16, outw16, outb, logits);
}

// Round 19
// 1484.583 us; speedup vs baseline: 1.1027x; 1.0023x over previous
//
#include <hip/hip_runtime.h>
#include <math.h>

typedef __attribute__((ext_vector_type(8))) short bf16x8;
typedef __attribute__((ext_vector_type(4))) float f32x4;
typedef __attribute__((ext_vector_type(8))) _Float16 f16x8;
typedef unsigned short ushort_t;

#define T_STEPS 64
#define BATCH   64
#define VOCAB   32000
#define EMB     512
#define HID     1024
#define G4      4096

__device__ __forceinline__ unsigned short f2bf(float x) {
    unsigned u = __builtin_bit_cast(unsigned, x);
    u += 0x7FFFu + ((u >> 16) & 1u);
    return (unsigned short)(u >> 16);
}
__device__ __forceinline__ float bf2f(unsigned short h) {
    unsigned u = ((unsigned)h) << 16;
    return __builtin_bit_cast(float, u);
}
__device__ __forceinline__ unsigned pack2(unsigned short a, unsigned short b) {
    return (unsigned)a | ((unsigned)b << 16);
}
__device__ __forceinline__ unsigned short f2h(float x) {
    return __builtin_bit_cast(unsigned short, (_Float16)x);
}
__device__ __forceinline__ float h2f(unsigned short h) {
    return (float)__builtin_bit_cast(_Float16, h);
}
__device__ __forceinline__ f32x4 ntload4(const float* p) {
    return __builtin_nontemporal_load((const f32x4*)p);
}

// packed A-fragment offset for 16x16x32 MFMA (M16 = row-groups of 16):
__device__ __forceinline__ size_t packA_off(int row, int k, int M16) {
    return ((size_t)((k >> 5) * M16 + (row >> 4))) * 512 +
           ((k & 31) >> 3) * 128 + (row & 15) * 8 + (k & 7);
}

// ---------------------------------------------------------------------------
// emb GEMM, depth-2 pipelined (round-14 win, kept).
// ---------------------------------------------------------------------------
__launch_bounds__(512, 2)
__global__ void gemm_emb(const float* __restrict__ A, const ushort_t* __restrict__ Bp,
                         float* __restrict__ C) {
    __shared__ _Float16 AhS[2][128][40];
    const int tid = threadIdx.x;
    const int row0 = blockIdx.x * 128;
    const int z = blockIdx.y;
    const int kBeg = z * 4000;
    const int kb8  = z * 500;
    C += (size_t)z * 4096 * EMB;

    const int l = tid & 63, w = tid >> 6;
    const int wm = w >> 2, wn = w & 3;
    const int lr = l & 15, lk = l >> 4;

    const int ar = tid >> 2, ak8 = (tid & 3) << 3;
    const float* Abase = A + (size_t)(row0 + ar) * VOCAB + kBeg + ak8;

    f32x4 acc[4][8];
#pragma unroll
    for (int m = 0; m < 4; ++m)
#pragma unroll
        for (int n = 0; n < 8; ++n)
#pragma unroll
            for (int r = 0; r < 4; ++r) acc[m][n][r] = 0.f;

    auto loadB = [&](int k, f16x8* dst) {
#pragma unroll
        for (int n = 0; n < 8; ++n) {
            int g = wn * 8 + n;
            dst[n] = *(const f16x8*)(Bp + ((size_t)g * 4000 + kb8 + k * 4 + lk) * 128 + lr * 8);
        }
    };
    auto loadA = [&](int k, f32x4& v0, f32x4& v1) {
        const float* ap = Abase + k * 32;
        v0 = ntload4(ap); v1 = ntload4(ap + 4);
    };
    auto storeA = [&](int buf, f32x4 v0, f32x4 v1) {
        f16x8 hv;
        hv[0] = (_Float16)v0[0]; hv[1] = (_Float16)v0[1];
        hv[2] = (_Float16)v0[2]; hv[3] = (_Float16)v0[3];
        hv[4] = (_Float16)v1[0]; hv[5] = (_Float16)v1[1];
        hv[6] = (_Float16)v1[2]; hv[7] = (_Float16)v1[3];
        *(f16x8*)&AhS[buf][ar][ak8] = hv;
    };
    auto mfmaStep = [&](int buf, f16x8* bset) {
        f16x8 a[4];
#pragma unroll
        for (int m = 0; m < 4; ++m)
            a[m] = *(const f16x8*)&AhS[buf][wm * 64 + m * 16 + lr][lk * 8];
#pragma unroll
        for (int m = 0; m < 4; ++m)
#pragma unroll
            for (int n = 0; n < 8; ++n)
                acc[m][n] = __builtin_amdgcn_mfma_f32_16x16x32_f16(a[m], bset[n], acc[m][n], 0, 0, 0);
    };

    f16x8 bA[8], bB[8];
    f32x4 a0A, a1A, a0B, a1B;
    {
        f32x4 t0, t1;
        loadA(0, t0, t1); storeA(0, t0, t1);
        loadA(1, a0A, a1A);
        loadB(0, bA); loadB(1, bB);
        __syncthreads();
    }
    for (int k = 0; k < 124; k += 2) {
        if (k + 2 < 125) loadA(k + 2, a0B, a1B);
        mfmaStep(0, bA);
        if (k + 2 < 125) loadB(k + 2, bA);
        storeA(1, a0A, a1A);
        __syncthreads();
        if (k + 3 < 125) loadA(k + 3, a0A, a1A);
        mfmaStep(1, bB);
        if (k + 3 < 125) loadB(k + 3, bB);
        if (k + 2 < 125) storeA(0, a0B, a1B);
        __syncthreads();
    }
    mfmaStep(0, bA);

    constexpr float invScale = 1.f / 256.f;
#pragma unroll
    for (int n = 0; n < 8; ++n) {
        int col = (wn * 8 + n) * 16 + lr;
#pragma unroll
        for (int m = 0; m < 4; ++m) {
            int rbase = row0 + wm * 64 + m * 16 + lk * 4;
#pragma unroll
            for (int r = 0; r < 4; ++r)
                C[(size_t)(rbase + r) * EMB + col] = acc[m][n][r] * invScale;
        }
    }
}

// ---------------------------------------------------------------------------
// fp16 GEMM (A fp32 -> LDS, B packed direct). Kept for z0x (small).
// ---------------------------------------------------------------------------
template<int BM, int BN, int NW_M, int NW_N, bool NTA, bool NTC>
__launch_bounds__(NW_M * NW_N * 64)
__global__ void gemm_a32b16(const float* __restrict__ A, const ushort_t* __restrict__ Bp,
                            float* __restrict__ C, int lda, int ldc, int K8,
                            int KCHUNK, size_t chunkStride, float invScale) {
    constexpr int THREADS = NW_M * NW_N * 64;
    constexpr int MF = BM / NW_M / 16;
    constexpr int NF = BN / NW_N / 16;
    __shared__ _Float16 AhS[BM][40];

    const int tid  = threadIdx.x;
    const int row0 = blockIdx.y * BM;
    const int gBase = blockIdx.x * (BN / 16);
    const int kBeg = blockIdx.z * KCHUNK;
    C += (size_t)blockIdx.z * chunkStride;

    const int l = tid & 63, w = tid >> 6;
    const int wm = w / NW_N, wn = w % NW_N;
    const int lr = l & 15, lk = l >> 4;

    f32x4 acc[MF][NF];
#pragma unroll
    for (int m = 0; m < MF; ++m)
#pragma unroll
        for (int n = 0; n < NF; ++n)
#pragma unroll
            for (int r = 0; r < 4; ++r) acc[m][n][r] = 0.f;

    constexpr int AI = BM * 4 / THREADS;

    for (int k0 = 0; k0 < KCHUNK; k0 += 32) {
#pragma unroll
        for (int i = 0; i < AI; ++i) {
            int f = tid + i * THREADS;
            int r = f >> 2, k8 = (f & 3) << 3;
            const float* ap = A + (size_t)(row0 + r) * lda + kBeg + k0 + k8;
            f32x4 v0, v1;
            if (NTA) { v0 = ntload4(ap); v1 = ntload4(ap + 4); }
            else     { v0 = *(const f32x4*)ap; v1 = *(const f32x4*)(ap + 4); }
            f16x8 hv;
            hv[0] = (_Float16)v0[0]; hv[1] = (_Float16)v0[1];
            hv[2] = (_Float16)v0[2]; hv[3] = (_Float16)v0[3];
            hv[4] = (_Float16)v1[0]; hv[5] = (_Float16)v1[1];
            hv[6] = (_Float16)v1[2]; hv[7] = (_Float16)v1[3];
            *(f16x8*)&AhS[r][k8] = hv;
        }
        __syncthreads();
        const size_t kRow = (size_t)((kBeg + k0) >> 3) + lk;
        f16x8 a[MF], b[NF];
#pragma unroll
        for (int n = 0; n < NF; ++n) {
            int g = gBase + wn * NF + n;
            b[n] = *(const f16x8*)(Bp + ((size_t)g * K8 + kRow) * 128 + lr * 8);
        }
#pragma unroll
        for (int m = 0; m < MF; ++m)
            a[m] = *(const f16x8*)&AhS[wm * MF * 16 + m * 16 + lr][lk * 8];
#pragma unroll
        for (int m = 0; m < MF; ++m)
#pragma unroll
            for (int n = 0; n < NF; ++n)
                acc[m][n] = __builtin_amdgcn_mfma_f32_16x16x32_f16(a[m], b[n], acc[m][n], 0, 0, 0);
        __syncthreads();
    }

#pragma unroll
    for (int n = 0; n < NF; ++n) {
        int col = (gBase + wn * NF + n) * 16 + lr;
#pragma unroll
        for (int m = 0; m < MF; ++m) {
            int rbase = row0 + wm * MF * 16 + m * 16 + lk * 4;
#pragma unroll
            for (int r = 0; r < 4; ++r) {
                float v = acc[m][n][r] * invScale;
                float* cp = &C[(size_t)(rbase + r) * ldc + col];
                if (NTC) __builtin_nontemporal_store(v, cp);
                else *cp = v;
            }
        }
    }
}

// sum 8 split-K partials
__global__ void reduce8(const float* __restrict__ zp, float* __restrict__ out, size_t cs) {
    size_t i = ((size_t)blockIdx.x * 256 + threadIdx.x) * 4;
    f32x4 a = *(const f32x4*)(zp + i);
#pragma unroll
    for (int c = 1; c < 8; ++c) {
        f32x4 b = *(const f32x4*)(zp + c * cs + i);
        a += b;
    }
    *(f32x4*)(out + i) = a;
}

// ---------------------------------------------------------------------------
// fp32 -> packed fp16 single plane (scaled x256). PERM = gate-interleave.
// ---------------------------------------------------------------------------
template<bool PERM>
__launch_bounds__(256)
__global__ void wcv16(const float* __restrict__ W, ushort_t* __restrict__ Wp,
                      int Krows, int ldW, float scale) {
    __shared__ float tile[32][33];
    const int k0 = blockIdx.x * 32;
    const int n0 = blockIdx.y * 32;
    const int tid = threadIdx.x;
#pragma unroll
    for (int i = 0; i < 4; ++i) {
        int idx = tid + i * 256;
        int r = idx >> 5, c = idx & 31;
        tile[r][c] = W[(size_t)(k0 + r) * ldW + n0 + c];
    }
    __syncthreads();
    const int rn = tid >> 3;
    const int cq = (tid & 7) * 4;
    unsigned short h[4];
#pragma unroll
    for (int j = 0; j < 4; ++j) h[j] = f2h(tile[cq + j][rn] * scale);
    const int n = n0 + rn;
    const int p = PERM ? (((n & 1023) >> 2) * 16 + (n >> 10) * 4 + (n & 3)) : n;
    const int k = k0 + cq;
    size_t off = ((size_t)(p >> 4) * (Krows >> 3) + (k >> 3)) * 128 + (p & 15) * 8 + (k & 7);
    uint2 hp; hp.x = pack2(h[0], h[1]); hp.y = pack2(h[2], h[3]);
    *(uint2*)(Wp + off) = hp;
}

// ---------------------------------------------------------------------------
// LSTM layer-step body v2 (round-16 best): block handles 32 cols (2 groups),
// A-fragments loaded once, reused for both W column sets. red stride 36.
// ---------------------------------------------------------------------------
template<int K>
__device__ __forceinline__ void lstm_body2(
        float* red, int cg0,
        const ushort_t* Ah, const ushort_t* Al,
        const ushort_t* Wp,
        const float* xpart, const float* bias,
        float* c_state, float* histF,
        ushort_t* d1h, ushort_t* d1l,
        ushort_t* d2h, ushort_t* d2l) {
    const int tid = threadIdx.x;
    const int l = tid & 63, w = tid >> 6;
    const int lr = l & 15, lk = l >> 4;
    constexpr int spw = K >> 8;
    const size_t lane_off = (size_t)lk * 128 + lr * 8;
    const size_t wb0 = (size_t)cg0 * (K >> 3) * 128 + lane_off;
    const size_t wb1 = (size_t)(cg0 + 1) * (K >> 3) * 128 + lane_off;

    f32x4 acc0[4], acc1[4];
#pragma unroll
    for (int m = 0; m < 4; ++m)
#pragma unroll
        for (int r = 0; r < 4; ++r) { acc0[m][r] = 0.f; acc1[m][r] = 0.f; }

    const int s0 = w * spw;
    const ushort_t* wptr0 = Wp + wb0 + (size_t)s0 * 512;
    const ushort_t* wptr1 = Wp + wb1 + (size_t)s0 * 512;
    const ushort_t* aptr = Ah + (size_t)s0 * 4 * 512 + l * 8;
    const ushort_t* lptr = Al + (size_t)s0 * 4 * 512 + l * 8;
#pragma unroll
    for (int s = 0; s < spw; ++s) {
        f16x8 bw0 = *(const f16x8*)(wptr0 + (size_t)s * 512);
        f16x8 bw1 = *(const f16x8*)(wptr1 + (size_t)s * 512);
#pragma unroll
        for (int m = 0; m < 4; ++m) {
            f16x8 ah = *(const f16x8*)(aptr + (size_t)(s * 4 + m) * 512);
            f16x8 al = *(const f16x8*)(lptr + (size_t)(s * 4 + m) * 512);
            acc0[m] = __builtin_amdgcn_mfma_f32_16x16x32_f16(ah, bw0, acc0[m], 0, 0, 0);
            acc0[m] = __builtin_amdgcn_mfma_f32_16x16x32_f16(al, bw0, acc0[m], 0, 0, 0);
            acc1[m] = __builtin_amdgcn_mfma_f32_16x16x32_f16(ah, bw1, acc1[m], 0, 0, 0);
            acc1[m] = __builtin_amdgcn_mfma_f32_16x16x32_f16(al, bw1, acc1[m], 0, 0, 0);
        }
    }
#pragma unroll
    for (int m = 0; m < 4; ++m) {
        *(f32x4*)&red[(w * 64 + l) * 36 + m * 4]      = acc0[m];
        *(f32x4*)&red[(w * 64 + l) * 36 + 16 + m * 4] = acc1[m];
    }
    __syncthreads();

    {
        const int gl = tid >> 8;
        const int tt = tid & 255;
        const int r = tt >> 2, v = tt & 3;
        const int m = r >> 4, lkq = (r >> 2) & 3, reg = r & 3;
        const int u = (cg0 + gl) * 4 + v;
        constexpr float invS = 1.f / 65536.f;
        float z[4];
#pragma unroll
        for (int j = 0; j < 4; ++j) {
            const int c = j * 4 + v;
            float s = 0.f;
#pragma unroll
            for (int ww = 0; ww < 8; ++ww)
                s += red[(ww * 64 + lkq * 16 + c) * 36 + gl * 16 + m * 4 + reg];
            s = s * invS + bias[j * 1024 + u];
            if (xpart)
                s += __builtin_nontemporal_load(&xpart[(size_t)r * 4096 + j * 1024 + u]);
            z[j] = s;
        }
        float f = 1.f / (1.f + expf(-z[0]));
        float i = 1.f / (1.f + expf(-z[1]));
        float o = 1.f / (1.f + expf(-z[2]));
        float g = tanhf(z[3]);
        const int cidx = r * 1024 + u;
        float cn = f * c_state[cidx] + i * g;
        c_state[cidx] = cn;
        float hn = o * tanhf(cn);
        __builtin_nontemporal_store(hn, &histF[cidx]);
        float hs = hn * 256.f;
        unsigned short hh = f2h(hs);
        unsigned short hl = f2h(hs - h2f(hh));
        size_t o1 = packA_off(r, u, 4);
        d1h[o1] = hh; d1l[o1] = hl;
        if (d2h) {
            size_t o2 = packA_off(r, u, 4);
            d2h[o2] = hh; d2l[o2] = hl;
        }
    }
    __syncthreads();
}

// ---------------------------------------------------------------------------
// Pipelined pair dispatch (round-16 best): 256 blocks; 0..127 -> layer0(t),
// 128..255 -> layer1(t-1), 32 cols each.
// ---------------------------------------------------------------------------
__launch_bounds__(512)
__global__ void lstm_pair(int active0, int active1,
        const ushort_t* Ah0, const ushort_t* Al0, const ushort_t* Wp0,
        const float* xpart0, const float* bias0,
        float* c0, float* hist0,
        ushort_t* d1h0, ushort_t* d1l0, ushort_t* d2h0, ushort_t* d2l0,
        const ushort_t* Ah1, const ushort_t* Al1, const ushort_t* Wp1,
        const float* bias1, float* c1, float* hist1,
        ushort_t* d1h1, ushort_t* d1l1) {
    __shared__ float red[512 * 36];
    const int b = blockIdx.x;
    if (b < 128) {
        if (!active0) return;
        lstm_body2<1024>(red, b * 2, Ah0, Al0, Wp0, xpart0, bias0,
                         c0, hist0, d1h0, d1l0, d2h0, d2l0);
    } else {
        if (!active1) return;
        lstm_body2<2048>(red, (b - 128) * 2, Ah1, Al1, Wp1, nullptr, bias1,
                         c1, hist1, d1h1, d1l1, nullptr, nullptr);
    }
}

// ---------------------------------------------------------------------------
// gates + gating; emits gated as packed fp16 SINGLE A-fragment plane (x256).
// ---------------------------------------------------------------------------
__launch_bounds__(256)
__global__ void gates_gated(const float* __restrict__ h0s, const float* __restrict__ h1s,
                            const float* __restrict__ gw,
                            ushort_t* __restrict__ gA16) {
    const int r = blockIdx.x;
    const int tid = threadIdx.x;
    const float* h0r = h0s + (size_t)r * HID;
    const float* h1r = h1s + (size_t)r * HID;
    float p0 = 0.f, p1 = 0.f;
    for (int k = tid; k < HID; k += 256) {
        float v0 = h0r[k], v1 = h1r[k];
        p0 += v0 * gw[2 * k]     + v1 * gw[2 * (HID + k)];
        p1 += v0 * gw[2 * k + 1] + v1 * gw[2 * (HID + k) + 1];
    }
#pragma unroll
    for (int off = 32; off; off >>= 1) {
        p0 += __shfl_down(p0, off);
        p1 += __shfl_down(p1, off);
    }
    __shared__ float s0[4], s1[4];
    __shared__ float gg[2];
    if ((tid & 63) == 0) { s0[tid >> 6] = p0; s1[tid >> 6] = p1; }
    __syncthreads();
    if (tid == 0) {
        float a = s0[0] + s0[1] + s0[2] + s0[3];
        float b = s1[0] + s1[1] + s1[2] + s1[3];
        gg[0] = 1.f / (1.f + expf(-a));
        gg[1] = 1.f / (1.f + expf(-b));
    }
    __syncthreads();
    float g0 = gg[0], g1 = gg[1];
    const int n0 = tid * 4;
    unsigned short h[4];
#pragma unroll
    for (int j = 0; j < 4; ++j) {
        int n = n0 + j;
        h[j] = f2h((g0 * h0r[n] + g1 * h1r[n]) * 256.f);
    }
    uint2 hp; hp.x = pack2(h[0], h[1]); hp.y = pack2(h[2], h[3]);
    *(uint2*)(gA16 + packA_off(r, n0, 256)) = hp;
}

// ---------------------------------------------------------------------------
// logits GEMM v4 (round-13 best, final): fp16 single planes both sides,
// dbuf LDS with depth-1 register prefetch, row-major XCD swizzle, NT C stores.
// ---------------------------------------------------------------------------
__launch_bounds__(512)
__global__ void gemm_out_v4(const ushort_t* __restrict__ gA16, const ushort_t* __restrict__ Bp,
                            const float* __restrict__ bias, float* __restrict__ C) {
    __shared__ ushort_t AL[2][8192];
    __shared__ ushort_t BL[2][4096];

    const int tid = threadIdx.x;
    const int lin = (blockIdx.x & 7) * 500 + (blockIdx.x >> 3);   // 4000 % 8 == 0
    const int bi = lin / 250, bj = lin % 250;
    const int row0 = bi * 256, col0 = bj * 128;

    const int l = tid & 63, w = tid >> 6;
    const int wm = w >> 1, wn = w & 1;
    const int lr = l & 15, lk = l >> 4;

    const int aOff = tid * 8;                                 // shorts
    const size_t bBase = (size_t)(bj * 8 + (tid >> 6)) * 16384 + (tid & 63) * 8;

    f32x4 acc[4][4];
#pragma unroll
    for (int m = 0; m < 4; ++m)
#pragma unroll
        for (int n = 0; n < 4; ++n)
#pragma unroll
            for (int r = 0; r < 4; ++r) acc[m][n][r] = 0.f;

    // prologue: stage tile 0
    {
        const size_t cA = ((size_t)(bi * 16)) * 512;
        uint4 a0 = *(const uint4*)(gA16 + cA + aOff);
        uint4 a1 = *(const uint4*)(gA16 + cA + 4096 + aOff);
        uint4 b0 = *(const uint4*)(Bp + bBase);
        *(uint4*)&AL[0][aOff] = a0;
        *(uint4*)&AL[0][4096 + aOff] = a1;
        *(uint4*)&BL[0][aOff & 4095] = b0;
    }
    __syncthreads();

    uint4 rA0, rA1, rB;
    for (int k32 = 0; k32 < 32; ++k32) {
        const int cur = k32 & 1, nxt = cur ^ 1;
        const bool hasNext = (k32 < 31);
        if (hasNext) {
            const size_t cA = ((size_t)((k32 + 1) * 256 + bi * 16)) * 512;
            rA0 = *(const uint4*)(gA16 + cA + aOff);
            rA1 = *(const uint4*)(gA16 + cA + 4096 + aOff);
            rB  = *(const uint4*)(Bp + bBase + (size_t)(k32 + 1) * 512);
        }
        f16x8 a[4], b[4];
#pragma unroll
        for (int m = 0; m < 4; ++m)
            a[m] = *(const f16x8*)&AL[cur][(wm * 4 + m) * 512 + l * 8];
#pragma unroll
        for (int n = 0; n < 4; ++n)
            b[n] = *(const f16x8*)&BL[cur][(wn * 4 + n) * 512 + l * 8];
#pragma unroll
        for (int m = 0; m < 4; ++m)
#pragma unroll
            for (int n = 0; n < 4; ++n)
                acc[m][n] = __builtin_amdgcn_mfma_f32_16x16x32_f16(a[m], b[n], acc[m][n], 0, 0, 0);
        if (hasNext) {
            *(uint4*)&AL[nxt][aOff] = rA0;
            *(uint4*)&AL[nxt][4096 + aOff] = rA1;
            *(uint4*)&BL[nxt][aOff & 4095] = rB;
        }
        __syncthreads();
    }

    constexpr float invScale = 1.f / 65536.f;
#pragma unroll
    for (int n = 0; n < 4; ++n) {
        int col = col0 + wn * 64 + n * 16 + lr;
        float bv = bias[col];
#pragma unroll
        for (int m = 0; m < 4; ++m) {
            int rbase = row0 + wm * 64 + m * 16 + lk * 4;
#pragma unroll
            for (int r = 0; r < 4; ++r)
                __builtin_nontemporal_store(acc[m][n][r] * invScale + bv,
                                            &C[(size_t)(rbase + r) * VOCAB + col]);
        }
    }
}

// ---------------------------------------------------------------------------
extern "C" void kernel_launch(void* const* d_in, const int* in_sizes, int n_in,
                              void* d_out, int out_size, void* d_ws, size_t ws_size,
                              hipStream_t stream) {
    const float* inputs = (const float*)d_in[0];
    const float* embm   = (const float*)d_in[1];
    const float* w0     = (const float*)d_in[2];
    const float* b0     = (const float*)d_in[3];
    const float* w1     = (const float*)d_in[4];
    const float* b1     = (const float*)d_in[5];
    const float* gw     = (const float*)d_in[6];
    const float* outw   = (const float*)d_in[7];
    const float* outb   = (const float*)d_in[8];
    float* logits = (float*)d_out;

    // ---- workspace layout (floats) ----
    float* ws    = (float*)d_ws;
    float* emb   = ws;                          // 2,097,152
    float* h0s   = ws + 2097152;                // 4,194,304
    float* h1s   = ws + 6291456;                // 4,194,304
    ushort_t* gA16 = (ushort_t*)(ws + 10485760); // 4,194,304 shorts
    float* c0    = ws + 14942208;               // 65,536
    float* c1    = ws + 15007744;               // 65,536
    ushort_t* hpB = (ushort_t*)(ws + 15073280); // 786,432 shorts
    ushort_t* outw16 = (ushort_t*)(ws + 15466496); // 32,768,000 shorts

    ushort_t* hp0h[2] = { hpB,            hpB + 65536 };
    ushort_t* hp0l[2] = { hpB + 131072,   hpB + 196608 };
    ushort_t* hp1h[2] = { hpB + 262144,   hpB + 393216 };
    ushort_t* hp1l[2] = { hpB + 524288,   hpB + 655360 };

    // ---- d_out doubles as scratch before logits ----
    float* zpEmb = (float*)d_out;                            // 16,777,216 f
    float* z0x   = (float*)d_out + 16777216;                 // 16,777,216 f
    ushort_t* wt0 = (ushort_t*)((float*)d_out + 33554432);   // 4,194,304 shorts
    ushort_t* wt1 = wt0 + 4194304;                           // 8,388,608 shorts
    ushort_t* embm16 = wt1 + 8388608;                        // 16,384,000 shorts
    ushort_t* w0x16  = embm16 + 16384000;                    // 2,097,152 shorts

    // zero c0, c1, h packed planes (contiguous region)
    (void)hipMemsetAsync(c0, 0, (size_t)524288 * sizeof(float), stream);

    // pre-convert operands to packed fp16 planes (scaled x256)
    wcv16<false><<<dim3(1000, 16), 256, 0, stream>>>(embm, embm16, VOCAB, EMB, 256.f);
    wcv16<false><<<dim3(16, 128), 256, 0, stream>>>(w0, w0x16, EMB, G4, 256.f);
    wcv16<false><<<dim3(32, 1000), 256, 0, stream>>>(outw, outw16, HID, VOCAB, 256.f);
    // LSTM weights -> fp16 single, gate-interleaved packed planes
    wcv16<true><<<dim3(32, 128), 256, 0, stream>>>(w0 + (size_t)512 * G4, wt0, 1024, G4, 256.f);
    wcv16<true><<<dim3(64, 128), 256, 0, stream>>>(w1, wt1, 2048, G4, 256.f);

    // emb = inputs @ embm : split-K x8, depth-2 pipelined
    gemm_emb<<<dim3(32, 8), 512, 0, stream>>>(inputs, embm16, zpEmb);
    reduce8<<<2048, 256, 0, stream>>>(zpEmb, emb, (size_t)4096 * EMB);

    // z0x = emb @ w0[:512,:]  (original column order; NT C stores)
    gemm_a32b16<128, 128, 2, 2, false, true><<<dim3(32, 32, 1), 256, 0, stream>>>(
        emb, w0x16, z0x, EMB, G4, EMB / 8, EMB, 0, 1.f / 256.f);

    // pipelined LSTM: dispatch t runs layer0(t) || layer1(t-1); 65 dispatches
    for (int t = 0; t <= T_STEPS; ++t) {
        const int p0 = t & 1, q0 = (t + 1) & 1;
        const int s  = t - 1, ss = s < 0 ? 0 : s;
        const int p1 = ss & 1, q1 = (ss + 1) & 1;
        lstm_pair<<<256, 512, 0, stream>>>(
            (t < T_STEPS) ? 1 : 0, (t >= 1) ? 1 : 0,
            hp0h[p0], hp0l[p0], wt0,
            z0x + (size_t)(t < T_STEPS ? t : 0) * 262144, b0,
            c0, h0s + (size_t)(t < T_STEPS ? t : 0) * 65536,
            hp0h[q0], hp0l[q0], hp1h[p0], hp1l[p0],
            hp1h[p1], hp1l[p1], wt1,
            b1, c1, h1s + (size_t)ss * 65536,
            hp1h[q1] + 65536, hp1l[q1] + 65536);
    }

    // gating -> packed fp16 single A plane (x256)
    gates_gated<<<4096, 256, 0, stream>>>(h0s, h1s, gw, gA16);

    // logits = gated @ outw + outb  (fp16 single both sides, NT C stores)
    gemm_out_v4<<<4000, 512, 0, stream>>>(gA16, outw16, outb, logits);
}